// Round 10
// baseline (181.706 us; speedup 1.0000x reference)
//
#include <hip/hip_runtime.h>

#define B_ 2
#define L_ 2048
#define E_ 1024
#define H_ 16
#define M_ (B_*L_)
#define LOG2E 1.4426950408889634f

typedef unsigned short u16;

using bf16x8 = __attribute__((ext_vector_type(8))) __bf16;
using f32x4  = __attribute__((ext_vector_type(4))) float;
using s16x4  = __attribute__((ext_vector_type(4))) short;
using s16x8  = __attribute__((ext_vector_type(8))) short;

__device__ inline float b2f(u16 u) {
    union { unsigned u; float f; } x; x.u = ((unsigned)u) << 16; return x.f;
}
// cheap round-half-up bf16 convert: 2 VALU ops vs 4 for RNE (tie bias negligible)
__device__ inline unsigned f2bu(float f) {
    union { float f; unsigned u; } x; x.f = f;
    return (x.u + 0x8000u) >> 16;
}
__device__ inline u16 f2b(float f) { return (u16)f2bu(f); }

// K=16 bf16 MFMA: D = A*B + C with 4 bf16 per lane per operand.
__device__ inline f32x4 mfma16(s16x4 a, s16x4 b, f32x4 c) {
#if __has_builtin(__builtin_amdgcn_mfma_f32_16x16x16bf16_1k)
    return __builtin_amdgcn_mfma_f32_16x16x16bf16_1k(a, b, c, 0, 0, 0);
#else
    union { s16x8 s; bf16x8 v; } a8, b8;
    a8.s = (s16x8){a[0], a[1], a[2], a[3], 0, 0, 0, 0};
    b8.s = (s16x8){b[0], b[1], b[2], b[3], 0, 0, 0, 0};
    return __builtin_amdgcn_mfma_f32_16x16x32_bf16(a8.v, b8.v, c, 0, 0, 0);
#endif
}

// async global->LDS, 16B per lane; lds dest = base + lane*16 (wave-uniform base)
__device__ inline void gld16(const u16* g, u16* l) {
    __builtin_amdgcn_global_load_lds((const __attribute__((address_space(1))) void*)g,
                                     (__attribute__((address_space(3))) void*)l, 16, 0, 0);
}

// (qt,ck) items for 128-q bands, 512-key chunks; code = qt*4+ck.
// nch(qt) = qt/4+1; full chunks cost 8 tiles, last chunk costs 2*(qt%4)+2.
// Sorted cost-descending (longest bands first within each cost class).
__constant__ unsigned short ATTN_MAP[40] = {
    63,62,61,60, 58,57,56, 54,53,52, 50,49,48, 46,45,44,
    41,40, 37,36, 33,32, 29,28, 24, 20, 16, 12,   // cost 8 (28)
    59,42,25,8,                                    // cost 6
    55,38,21,4,                                    // cost 4
    51,34,17,0                                     // cost 2
};

__device__ inline int slot_base(int qt) {   // chunk-slot base for bands qt>=4
    return (qt < 8) ? (qt - 4) * 2 : (qt < 12) ? 8 + (qt - 8) * 3 : 20 + (qt - 12) * 4;
}

// ---------------- casts + vmean zero in one launch ----------------
__global__ __launch_bounds__(256) void cast_all(
    const float* __restrict__ hs, const float* __restrict__ w0, const float* __restrict__ w1,
    const float* __restrict__ w2, const float* __restrict__ w3,
    u16* __restrict__ oh, u16* __restrict__ o0, u16* __restrict__ o1,
    u16* __restrict__ o2, u16* __restrict__ o3, float* __restrict__ vmean)
{
    int bid = blockIdx.x;
    if (bid == 8192) {   // zero vmean (2048 floats)
        float4 z = make_float4(0.f, 0.f, 0.f, 0.f);
        ((float4*)vmean)[threadIdx.x * 2]     = z;
        ((float4*)vmean)[threadIdx.x * 2 + 1] = z;
        return;
    }
    const float* in; u16* out; int base;
    if (bid < 4096) { in = hs; out = oh; base = bid; }
    else {
        int w = (bid - 4096) >> 10, r = (bid - 4096) & 1023;
        base = r;
        switch (w) {
            case 0: in = w0; out = o0; break;
            case 1: in = w1; out = o1; break;
            case 2: in = w2; out = o2; break;
            default: in = w3; out = o3; break;
        }
    }
    int i = base * 256 + threadIdx.x;
    float4 f = ((const float4*)in)[i];
    unsigned lo = f2bu(f.x) | (f2bu(f.y) << 16);
    unsigned hi = f2bu(f.z) | (f2bu(f.w) << 16);
    ((uint2*)out)[i] = make_uint2(lo, hi);
}

// ---------------- fused QKV GEMM: 128x128 tile, BK=32, global_load_lds ----------------
// Q gets (x+bq)*0.125*log2e; K plain; V gets +bv, LDS-transposed, written coalesced to
// vt[b][h][d][l] with fused vmean atomic accumulation (vmean pre-zeroed).
__global__ __launch_bounds__(256, 3) void gemm_qkv(
    const u16* __restrict__ A, const u16* __restrict__ Wq, const u16* __restrict__ Wk,
    const u16* __restrict__ Wv, const float* __restrict__ bq, const float* __restrict__ bv,
    u16* __restrict__ Qo, u16* __restrict__ Ko, u16* __restrict__ vt,
    float* __restrict__ vmean)
{
    __shared__ u16 As[128 * 32];
    __shared__ u16 Bs[128 * 32];
    __shared__ u16 Ts[128][136];   // V transpose staging (16B-aligned rows)
    const int tid = threadIdx.x, wave = tid >> 6, lane = tid & 63;
    const int qg = lane >> 4, ln = lane & 15;
    const int wm = wave >> 1, wn = wave & 1;
    const int m0 = blockIdx.x * 128;
    const int nG = blockIdx.y * 128;
    const int wsel = nG >> 10;
    const u16* __restrict__ Wp = wsel == 0 ? Wq : (wsel == 1 ? Wk : Wv);
    const int n0 = nG & 1023;

    const int srow = lane >> 2, scol = (lane & 3) * 8;
    const u16* ga1 = A + (size_t)(m0 + wave * 16 + srow) * E_ + scol;
    const u16* ga2 = A + (size_t)(m0 + (wave + 4) * 16 + srow) * E_ + scol;
    const u16* gb1 = Wp + (size_t)(n0 + wave * 16 + srow) * E_ + scol;
    const u16* gb2 = Wp + (size_t)(n0 + (wave + 4) * 16 + srow) * E_ + scol;

    f32x4 acc[4][4] = {};
    for (int ko = 0; ko < E_; ko += 32) {
        gld16(ga1 + ko, &As[wave * 512]);
        gld16(ga2 + ko, &As[(wave + 4) * 512]);
        gld16(gb1 + ko, &Bs[wave * 512]);
        gld16(gb2 + ko, &Bs[(wave + 4) * 512]);
        __syncthreads();
        bf16x8 af[4], bfr[4];
#pragma unroll
        for (int r = 0; r < 4; ++r) af[r]  = *(const bf16x8*)&As[(wm * 64 + r * 16 + ln) * 32 + qg * 8];
#pragma unroll
        for (int c = 0; c < 4; ++c) bfr[c] = *(const bf16x8*)&Bs[(wn * 64 + c * 16 + ln) * 32 + qg * 8];
#pragma unroll
        for (int r = 0; r < 4; ++r)
#pragma unroll
            for (int c = 0; c < 4; ++c)
                acc[r][c] = __builtin_amdgcn_mfma_f32_16x16x32_bf16(af[r], bfr[c], acc[r][c], 0, 0, 0);
        __syncthreads();
    }

    if (wsel < 2) {
        u16* Op = wsel == 0 ? Qo : Ko;
        const float* bias = wsel == 0 ? bq : nullptr;
        const float scale = (wsel == 0) ? 0.125f * LOG2E : 1.0f;
#pragma unroll
        for (int c = 0; c < 4; ++c) {
            int col = n0 + wn * 64 + c * 16 + ln;
            float bb = bias ? bias[col] : 0.0f;
#pragma unroll
            for (int r = 0; r < 4; ++r) {
#pragma unroll
                for (int i = 0; i < 4; ++i) {
                    int row = m0 + wm * 64 + r * 16 + qg * 4 + i;
                    Op[(size_t)row * E_ + col] = f2b((acc[r][c][i] + bb) * scale);
                }
            }
        }
    } else {
        // V: transpose through LDS, then coalesced vt stores + vmean atomics
#pragma unroll
        for (int c = 0; c < 4; ++c) {
            int cl = wn * 64 + c * 16 + ln;
            float bb = bv[n0 + cl];
#pragma unroll
            for (int r = 0; r < 4; ++r)
#pragma unroll
                for (int i = 0; i < 4; ++i)
                    Ts[cl][wm * 64 + r * 16 + qg * 4 + i] = f2b(acc[r][c][i] + bb);
        }
        __syncthreads();
        const int b = m0 >> 11;
        const int l0 = m0 & 2047;
        const int row = tid >> 1, seg = tid & 1;
        const int col = n0 + row;
        const int hh = col >> 6, d = col & 63;
        u16* dstrow = vt + ((size_t)((b * H_ + hh) * 64 + d)) * L_ + l0 + seg * 64;
        float s = 0.f;
#pragma unroll
        for (int g = 0; g < 8; ++g) {
            u16 t8[8];
            *(uint4*)t8 = *(const uint4*)&Ts[row][seg * 64 + g * 8];
#pragma unroll
            for (int j = 0; j < 8; ++j) s += b2f(t8[j]);
            *(uint4*)(dstrow + g * 8) = *(const uint4*)t8;
        }
        s += __shfl_xor(s, 1);
        if (seg == 0) atomicAdd(&vmean[(b * H_ + hh) * 64 + d], s * (1.0f / (float)L_));
    }
}

// ---------------- output GEMM: 128x64 tile (512 blocks, 2/CU), BK=32, f32 out ------------
__global__ __launch_bounds__(256, 3) void gemm_out(
    const u16* __restrict__ A, const u16* __restrict__ W,
    const float* __restrict__ bias, float* __restrict__ Cf)
{
    __shared__ u16 As[128 * 32];
    __shared__ u16 Bs[64 * 32];
    const int tid = threadIdx.x, wave = tid >> 6, lane = tid & 63;
    const int qg = lane >> 4, ln = lane & 15;
    const int wm = wave >> 1, wn = wave & 1;
    const int m0 = blockIdx.x * 128;
    const int n0 = blockIdx.y * 64;

    const int srow = lane >> 2, scol = (lane & 3) * 8;
    const u16* ga1 = A + (size_t)(m0 + wave * 16 + srow) * E_ + scol;
    const u16* ga2 = A + (size_t)(m0 + (wave + 4) * 16 + srow) * E_ + scol;
    const u16* gb1 = W + (size_t)(n0 + wave * 16 + srow) * E_ + scol;

    f32x4 acc[4][2] = {};
    for (int ko = 0; ko < E_; ko += 32) {
        gld16(ga1 + ko, &As[wave * 512]);
        gld16(ga2 + ko, &As[(wave + 4) * 512]);
        gld16(gb1 + ko, &Bs[wave * 512]);
        __syncthreads();
        bf16x8 af[4], bfr[2];
#pragma unroll
        for (int r = 0; r < 4; ++r) af[r]  = *(const bf16x8*)&As[(wm * 64 + r * 16 + ln) * 32 + qg * 8];
#pragma unroll
        for (int c = 0; c < 2; ++c) bfr[c] = *(const bf16x8*)&Bs[(wn * 32 + c * 16 + ln) * 32 + qg * 8];
#pragma unroll
        for (int r = 0; r < 4; ++r)
#pragma unroll
            for (int c = 0; c < 2; ++c)
                acc[r][c] = __builtin_amdgcn_mfma_f32_16x16x32_bf16(af[r], bfr[c], acc[r][c], 0, 0, 0);
        __syncthreads();
    }
#pragma unroll
    for (int c = 0; c < 2; ++c) {
        int col = n0 + wn * 32 + c * 16 + ln;
        float bb = bias[col];
#pragma unroll
        for (int r = 0; r < 4; ++r) {
#pragma unroll
            for (int i = 0; i < 4; ++i) {
                int row = m0 + wm * 64 + r * 16 + qg * 4 + i;
                Cf[(size_t)row * E_ + col] = acc[r][c][i] + bb;
            }
        }
    }
}

// ---------------- flash attention: 128-q bands, 8 waves x 16 q-rows, S^T register-P ------
// S^T = K Q^T (A=K,B=Q) => reg i holds key qg*4+i, col q=ln. P packed in-register as
// the B-operand of a K=16 PV MFMA: O^T[d][q] += V[d][key] P^T[key][q]. 8 waves share
// one K/V double-buffer (36.9 KB) -> ~24 waves/CU co-resident.
__global__ __launch_bounds__(512, 4) void attn_kernel(
    const u16* __restrict__ Q, const u16* __restrict__ K, const u16* __restrict__ Vt,
    const int* __restrict__ seq_len, const float* __restrict__ vmean,
    u16* __restrict__ ctx, u16* __restrict__ Opart, float* __restrict__ Lpart)
{
    __shared__ u16 Ks[2][64][72];   // [buf][key][feat]
    __shared__ u16 Vs[2][64][72];   // [buf][d][key]

    const int tid = threadIdx.x, wave = tid >> 6, lane = tid & 63;
    const int qg = lane >> 4, ln = lane & 15;
    const int bh = blockIdx.x & 31;
    const int code = ATTN_MAP[blockIdx.x >> 5];
    const int qt = code >> 2, ck = code & 3;
    const int b = bh >> 4, h = bh & 15;
    const int q0 = qt * 128;
    const int seq = seq_len[b];
    if (seq <= q0) return;                       // combine writes vmean rows

    const int kend_band = min(q0 + 128, seq);
    const int nch = (kend_band + 511) >> 9;
    if (ck >= nch) return;
    const bool direct = (nch == 1);
    const int kstart = ck << 9;
    const int kend_c = min(kend_band, kstart + 512);
    const int ntiles = (kend_c - kstart + 63) >> 6;
    const int wq0 = q0 + wave * 16;
    const int qr = wq0 + ln;                     // this lane's q-row

    // Q B-fragments
    bf16x8 qa[2];
    {
        const u16* qp = Q + (size_t)(b * L_ + qr) * E_ + h * 64;
        qa[0] = *(const bf16x8*)(qp + qg * 8);
        qa[1] = *(const bf16x8*)(qp + 32 + qg * 8);
    }

    f32x4 ot[4] = {};          // O^T: d = dt*16 + qg*4 + i, q = ln
    float lsum = 0.f;

    const int sr = tid >> 3, ss = (tid & 7) * 8;   // 512 threads -> 64 rows x 8 segs
    const u16* kbase = K + (size_t)(b * L_) * E_ + h * 64;
    const u16* vbase = Vt + (size_t)bh * 64 * L_;

    uint4 rk0 = *(const uint4*)(kbase + (size_t)(kstart + sr) * E_ + ss);
    uint4 rv0 = *(const uint4*)(vbase + (size_t)sr * L_ + kstart + ss);

    for (int kt = 0; kt < ntiles; ++kt) {
        const int kb0 = kstart + kt * 64;
        const int buf = kt & 1;
        *(uint4*)&Ks[buf][sr][ss] = rk0;
        *(uint4*)&Vs[buf][sr][ss] = rv0;
        __syncthreads();

        if (kt + 1 < ntiles) {
            const int kn = kb0 + 64;
            rk0 = *(const uint4*)(kbase + (size_t)(kn + sr) * E_ + ss);
            rv0 = *(const uint4*)(vbase + (size_t)sr * L_ + kn + ss);
        }

        // S^T = K Q^T: 4 key-tiles of 16 (keys kb0 + c*16 + qg*4 + i per reg)
        f32x4 st[4] = {};
#pragma unroll
        for (int t = 0; t < 2; ++t) {
#pragma unroll
            for (int c = 0; c < 4; ++c) {
                bf16x8 kb = *(const bf16x8*)&Ks[buf][c * 16 + ln][t * 32 + qg * 8];
                st[c] = __builtin_amdgcn_mfma_f32_16x16x32_bf16(kb, qa[t], st[c], 0, 0, 0);
            }
        }

        // softmax numerator in-register; pack P^T as K=16 B-operands
        const bool need_mask = (kb0 + 63) > wq0;
        s16x4 pb[4];
#pragma unroll
        for (int c = 0; c < 4; ++c) {
            const int keyb = kb0 + c * 16 + qg * 4;
            float p0 = exp2f(st[c][0]);
            float p1 = exp2f(st[c][1]);
            float p2 = exp2f(st[c][2]);
            float p3 = exp2f(st[c][3]);
            if (need_mask) {
                if (keyb > qr)     p0 = 0.f;
                if (keyb + 1 > qr) p1 = 0.f;
                if (keyb + 2 > qr) p2 = 0.f;
                if (keyb + 3 > qr) p3 = 0.f;
            }
            lsum += (p0 + p1) + (p2 + p3);
            union { s16x4 v; uint2 u; } pk;
            pk.u.x = f2bu(p0) | (f2bu(p1) << 16);
            pk.u.y = f2bu(p2) | (f2bu(p3) << 16);
            pb[c] = pk.v;
        }

        // O^T += V * P^T  (A = V[d][key] b64 frags from LDS, B = pb, K=16)
#pragma unroll
        for (int dt = 0; dt < 4; ++dt) {
#pragma unroll
            for (int c = 0; c < 4; ++c) {
                s16x4 vf = *(const s16x4*)&Vs[buf][dt * 16 + ln][c * 16 + qg * 4];
                ot[dt] = mfma16(vf, pb[c], ot[dt]);
            }
        }
    }

    // lsum: in-lane keys done; reduce across the 4 quad-groups (same q=ln)
    lsum += __shfl_xor(lsum, 16);
    lsum += __shfl_xor(lsum, 32);

    if (direct) {
        bool valid = qr < seq;
        float inv = valid ? (1.0f / lsum) : 0.f;
        u16* cp = ctx + ((size_t)(b * L_ + qr)) * E_ + h * 64;
#pragma unroll
        for (int dt = 0; dt < 4; ++dt) {
            uint2 w;
            if (valid) {
                w.x = f2bu(ot[dt][0] * inv) | (f2bu(ot[dt][1] * inv) << 16);
                w.y = f2bu(ot[dt][2] * inv) | (f2bu(ot[dt][3] * inv) << 16);
            } else {
                const float* vm = vmean + bh * 64 + dt * 16 + qg * 4;
                w.x = f2bu(vm[0]) | (f2bu(vm[1]) << 16);
                w.y = f2bu(vm[2]) | (f2bu(vm[3]) << 16);
            }
            *(uint2*)(cp + dt * 16 + qg * 4) = w;
        }
    } else {
        const int slot = slot_base(qt) + ck;
        const size_t pbase = ((size_t)bh * 36 + slot) * 128 + wave * 16 + ln;
        u16* op = Opart + pbase * 64;
#pragma unroll
        for (int dt = 0; dt < 4; ++dt) {
            uint2 w;
            w.x = f2bu(ot[dt][0]) | (f2bu(ot[dt][1]) << 16);
            w.y = f2bu(ot[dt][2]) | (f2bu(ot[dt][3]) << 16);
            *(uint2*)(op + dt * 16 + qg * 4) = w;
        }
        if (qg == 0) Lpart[pbase] = lsum;
    }
}

// ---------------- merge chunk partials, normalize, write ctx (128-row bands) ----------
__global__ __launch_bounds__(256) void attn_combine(
    const u16* __restrict__ Opart, const float* __restrict__ Lpart,
    const int* __restrict__ seq_len, const float* __restrict__ vmean,
    u16* __restrict__ ctx)
{
    const int qt = blockIdx.x, h = blockIdx.y, b = blockIdx.z;
    const int seq = seq_len[b];
    const int q0 = qt * 128;
    const int bh = b * H_ + h;
    int nch = 0;
    if (seq > q0) {
        nch = (min(q0 + 128, seq) + 511) >> 9;
        if (nch == 1) return;            // band written directly by attn_kernel
    }
    const int row = threadIdx.x >> 1, half = threadIdx.x & 1;
    const int qr = q0 + row;
    u16* dst = ctx + ((size_t)(b * L_ + qr)) * E_ + h * 64 + half * 32;
    if (nch == 0 || qr >= seq) {
        u16 t[32];
#pragma unroll
        for (int j = 0; j < 32; ++j) t[j] = f2b(vmean[bh * 64 + half * 32 + j]);
#pragma unroll
        for (int g = 0; g < 4; ++g) *(uint4*)(dst + g * 8) = *(uint4*)(t + g * 8);
        return;
    }
    const int sb = slot_base(qt);
    float acc[32] = {};
    float lt = 0.f;
    for (int ck = 0; ck < nch; ++ck) {
        const size_t pb = ((size_t)bh * 36 + sb + ck) * 128 + row;
        lt += Lpart[pb];
        const u16* op = Opart + pb * 64 + half * 32;
        u16 t[32];
#pragma unroll
        for (int g = 0; g < 4; ++g) *(uint4*)(t + g * 8) = *(const uint4*)(op + g * 8);
#pragma unroll
        for (int j = 0; j < 32; ++j) acc[j] += b2f(t[j]);
    }
    const float inv = 1.0f / lt;
    u16 t[32];
#pragma unroll
    for (int j = 0; j < 32; ++j) t[j] = f2b(acc[j] * inv);
#pragma unroll
    for (int g = 0; g < 4; ++g) *(uint4*)(dst + g * 8) = *(uint4*)(t + g * 8);
}

extern "C" void kernel_launch(void* const* d_in, const int* in_sizes, int n_in,
                              void* d_out, int out_size, void* d_ws, size_t ws_size,
                              hipStream_t stream) {
    const float* hs = (const float*)d_in[0];
    const int*   seq = (const int*)d_in[1];
    const float* Wq = (const float*)d_in[2];
    const float* bq = (const float*)d_in[3];
    const float* Wk = (const float*)d_in[4];
    const float* Wv = (const float*)d_in[5];
    const float* bv = (const float*)d_in[6];
    const float* Wo = (const float*)d_in[7];
    const float* bo = (const float*)d_in[8];
    float* out = (float*)d_out;

    char* ws = (char*)d_ws;
    u16* hs_b  = (u16*)(ws);                          // 8 MB
    u16* wq_b  = (u16*)(ws + ((size_t)8  << 20));
    u16* wk_b  = (u16*)(ws + ((size_t)10 << 20));
    u16* wv_b  = (u16*)(ws + ((size_t)12 << 20));
    u16* wo_b  = (u16*)(ws + ((size_t)14 << 20));
    u16* q_b   = (u16*)(ws + ((size_t)16 << 20));     // 8 MB
    u16* k_b   = (u16*)(ws + ((size_t)24 << 20));     // 8 MB
    u16* vt    = (u16*)(ws + ((size_t)32 << 20));     // 8 MB (transposed V)
    u16* ctx_b = (u16*)(ws + ((size_t)40 << 20));     // 8 MB
    u16* Opart = (u16*)(ws + ((size_t)48 << 20));     // 18.9 MB (36 slots x 32bh x 128x64)
    float* Lpart = (float*)(ws + ((size_t)67 << 20)); // 590 KB
    float* vmean = (float*)(ws + ((size_t)68 << 20)); // 8 KB

    cast_all<<<8193, 256, 0, stream>>>(hs, Wq, Wk, Wv, Wo, hs_b, wq_b, wk_b, wv_b, wo_b, vmean);

    gemm_qkv<<<dim3(M_/128, 3*E_/128), 256, 0, stream>>>(hs_b, wq_b, wk_b, wv_b, bq, bv,
                                                         q_b, k_b, vt, vmean);

    attn_kernel<<<dim3(40 * 32), 512, 0, stream>>>(q_b, k_b, vt, seq, vmean,
                                                   ctx_b, Opart, Lpart);

    attn_combine<<<dim3(16, H_, B_), 256, 0, stream>>>(Opart, Lpart, seq, vmean, ctx_b);

    gemm_out<<<dim3(M_/128, E_/64), 256, 0, stream>>>(ctx_b, wo_b, bo, out);
}

// Round 11
// 175.688 us; speedup vs baseline: 1.0343x; 1.0343x over previous
//
#include <hip/hip_runtime.h>

#define B_ 2
#define L_ 2048
#define E_ 1024
#define H_ 16
#define M_ (B_*L_)
#define LOG2E 1.4426950408889634f

typedef unsigned short u16;

using bf16x8 = __attribute__((ext_vector_type(8))) __bf16;
using f32x4  = __attribute__((ext_vector_type(4))) float;
using s16x4  = __attribute__((ext_vector_type(4))) short;
using s16x8  = __attribute__((ext_vector_type(8))) short;

__device__ inline float b2f(u16 u) {
    union { unsigned u; float f; } x; x.u = ((unsigned)u) << 16; return x.f;
}
// cheap round-half-up bf16 convert: 2 VALU ops vs 4 for RNE (tie bias negligible)
__device__ inline unsigned f2bu(float f) {
    union { float f; unsigned u; } x; x.f = f;
    return (x.u + 0x8000u) >> 16;
}
__device__ inline u16 f2b(float f) { return (u16)f2bu(f); }

// async global->LDS, 16B per lane; lds dest = base + lane*16 (wave-uniform base)
__device__ inline void gld16(const u16* g, u16* l) {
    __builtin_amdgcn_global_load_lds((const __attribute__((address_space(1))) void*)g,
                                     (__attribute__((address_space(3))) void*)l, 16, 0, 0);
}

// (qt,ck) work items sorted by chain length (tiles) descending; code = (qt<<2)|ck.
// chunks of 512 keys; 64-q bands; cost = min(8, qt+1-8*ck).
__constant__ unsigned short ATTN_MAP[80] = {
    124,125,126,127, 120,121,122, 116,117,118, 112,113,114, 108,109,110,
    104,105,106, 100,101,102, 96,97,98, 92,93,94,
    88,89, 84,85, 80,81, 76,77, 72,73, 68,69, 64,65, 60,61,
    56, 52, 48, 44, 40, 36, 32, 28,
    123, 90, 57, 24,
    119, 86, 53, 20,
    115, 82, 49, 16,
    111, 78, 45, 12,
    107, 74, 41, 8,
    103, 70, 37, 4,
    99,  66, 33, 0
};

__device__ inline int slot_base(int qt) {
    return (qt < 16) ? (qt - 8) * 2 : (qt < 24) ? 16 + (qt - 16) * 3 : 40 + (qt - 24) * 4;
}

// ---------------- casts + vmean zero in one launch ----------------
__global__ __launch_bounds__(256) void cast_all(
    const float* __restrict__ hs, const float* __restrict__ w0, const float* __restrict__ w1,
    const float* __restrict__ w2, const float* __restrict__ w3,
    u16* __restrict__ oh, u16* __restrict__ o0, u16* __restrict__ o1,
    u16* __restrict__ o2, u16* __restrict__ o3, float* __restrict__ vmean)
{
    int bid = blockIdx.x;
    if (bid == 8192) {   // zero vmean (2048 floats)
        float4 z = make_float4(0.f, 0.f, 0.f, 0.f);
        ((float4*)vmean)[threadIdx.x * 2]     = z;
        ((float4*)vmean)[threadIdx.x * 2 + 1] = z;
        return;
    }
    const float* in; u16* out; int base;
    if (bid < 4096) { in = hs; out = oh; base = bid; }
    else {
        int w = (bid - 4096) >> 10, r = (bid - 4096) & 1023;
        base = r;
        switch (w) {
            case 0: in = w0; out = o0; break;
            case 1: in = w1; out = o1; break;
            case 2: in = w2; out = o2; break;
            default: in = w3; out = o3; break;
        }
    }
    int i = base * 256 + threadIdx.x;
    float4 f = ((const float4*)in)[i];
    unsigned lo = f2bu(f.x) | (f2bu(f.y) << 16);
    unsigned hi = f2bu(f.z) | (f2bu(f.w) << 16);
    ((uint2*)out)[i] = make_uint2(lo, hi);
}

// ---------------- fused QKV GEMM: 128x128 tile, BK=32, global_load_lds ----------------
// Q gets (x+bq)*0.125*log2e; K plain; V gets +bv and is written TRANSPOSED to vt[b][h][d][l]
// with fused vmean atomic accumulation (vmean pre-zeroed).
__global__ __launch_bounds__(256, 3) void gemm_qkv(
    const u16* __restrict__ A, const u16* __restrict__ Wq, const u16* __restrict__ Wk,
    const u16* __restrict__ Wv, const float* __restrict__ bq, const float* __restrict__ bv,
    u16* __restrict__ Qo, u16* __restrict__ Ko, u16* __restrict__ vt,
    float* __restrict__ vmean)
{
    __shared__ u16 As[128 * 32];
    __shared__ u16 Bs[128 * 32];
    const int tid = threadIdx.x, wave = tid >> 6, lane = tid & 63;
    const int qg = lane >> 4, ln = lane & 15;
    const int wm = wave >> 1, wn = wave & 1;
    const int m0 = blockIdx.x * 128;
    const int nG = blockIdx.y * 128;
    const int wsel = nG >> 10;
    const u16* __restrict__ Wp = wsel == 0 ? Wq : (wsel == 1 ? Wk : Wv);
    const int n0 = nG & 1023;

    const int srow = lane >> 2, scol = (lane & 3) * 8;
    const u16* ga1 = A + (size_t)(m0 + wave * 16 + srow) * E_ + scol;
    const u16* ga2 = A + (size_t)(m0 + (wave + 4) * 16 + srow) * E_ + scol;
    const u16* gb1 = Wp + (size_t)(n0 + wave * 16 + srow) * E_ + scol;
    const u16* gb2 = Wp + (size_t)(n0 + (wave + 4) * 16 + srow) * E_ + scol;

    f32x4 acc[4][4] = {};
    for (int ko = 0; ko < E_; ko += 32) {
        gld16(ga1 + ko, &As[wave * 512]);
        gld16(ga2 + ko, &As[(wave + 4) * 512]);
        gld16(gb1 + ko, &Bs[wave * 512]);
        gld16(gb2 + ko, &Bs[(wave + 4) * 512]);
        __syncthreads();
        bf16x8 af[4], bfr[4];
#pragma unroll
        for (int r = 0; r < 4; ++r) af[r]  = *(const bf16x8*)&As[(wm * 64 + r * 16 + ln) * 32 + qg * 8];
#pragma unroll
        for (int c = 0; c < 4; ++c) bfr[c] = *(const bf16x8*)&Bs[(wn * 64 + c * 16 + ln) * 32 + qg * 8];
#pragma unroll
        for (int r = 0; r < 4; ++r)
#pragma unroll
            for (int c = 0; c < 4; ++c)
                acc[r][c] = __builtin_amdgcn_mfma_f32_16x16x32_bf16(af[r], bfr[c], acc[r][c], 0, 0, 0);
        __syncthreads();
    }

    if (wsel < 2) {
        u16* Op = wsel == 0 ? Qo : Ko;
        const float* bias = wsel == 0 ? bq : nullptr;
        const float scale = (wsel == 0) ? 0.125f * LOG2E : 1.0f;
#pragma unroll
        for (int c = 0; c < 4; ++c) {
            int col = n0 + wn * 64 + c * 16 + ln;
            float bb = bias ? bias[col] : 0.0f;
#pragma unroll
            for (int r = 0; r < 4; ++r) {
#pragma unroll
                for (int i = 0; i < 4; ++i) {
                    int row = m0 + wm * 64 + r * 16 + qg * 4 + i;
                    Op[(size_t)row * E_ + col] = f2b((acc[r][c][i] + bb) * scale);
                }
            }
        }
    } else {
        // V: write transposed vt[b][h][d][l] (packed 4 l's per store) + vmean atomics
        const int b = m0 >> 11;
        const int l0 = (m0 & 2047) + wm * 64 + qg * 4;
#pragma unroll
        for (int c = 0; c < 4; ++c) {
            int col = n0 + wn * 64 + c * 16 + ln;
            int hh = col >> 6, d = col & 63;
            float bb = bv[col];
            u16* vrow = vt + ((size_t)((b * H_ + hh) * 64 + d)) * L_ + l0;
            float colsum = 0.f;
#pragma unroll
            for (int r = 0; r < 4; ++r) {
                u16 tmp[4];
#pragma unroll
                for (int i = 0; i < 4; ++i) {
                    float v = acc[r][c][i] + bb;
                    colsum += v;
                    tmp[i] = f2b(v);
                }
                *(uint2*)(vrow + r * 16) = *(uint2*)tmp;
            }
            colsum += __shfl_xor(colsum, 16);
            colsum += __shfl_xor(colsum, 32);
            if (qg == 0) atomicAdd(&vmean[(b * H_ + hh) * 64 + d], colsum * (1.0f / (float)L_));
        }
    }
}

// ---------------- output GEMM: 128x64 tile (512 blocks, 2/CU), BK=32, f32 out ------------
__global__ __launch_bounds__(256, 3) void gemm_out(
    const u16* __restrict__ A, const u16* __restrict__ W,
    const float* __restrict__ bias, float* __restrict__ Cf)
{
    __shared__ u16 As[128 * 32];
    __shared__ u16 Bs[64 * 32];
    const int tid = threadIdx.x, wave = tid >> 6, lane = tid & 63;
    const int qg = lane >> 4, ln = lane & 15;
    const int wm = wave >> 1, wn = wave & 1;
    const int m0 = blockIdx.x * 128;
    const int n0 = blockIdx.y * 64;

    const int srow = lane >> 2, scol = (lane & 3) * 8;
    const u16* ga1 = A + (size_t)(m0 + wave * 16 + srow) * E_ + scol;
    const u16* ga2 = A + (size_t)(m0 + (wave + 4) * 16 + srow) * E_ + scol;
    const u16* gb1 = W + (size_t)(n0 + wave * 16 + srow) * E_ + scol;

    f32x4 acc[4][2] = {};
    for (int ko = 0; ko < E_; ko += 32) {
        gld16(ga1 + ko, &As[wave * 512]);
        gld16(ga2 + ko, &As[(wave + 4) * 512]);
        gld16(gb1 + ko, &Bs[wave * 512]);
        __syncthreads();
        bf16x8 af[4], bfr[2];
#pragma unroll
        for (int r = 0; r < 4; ++r) af[r]  = *(const bf16x8*)&As[(wm * 64 + r * 16 + ln) * 32 + qg * 8];
#pragma unroll
        for (int c = 0; c < 2; ++c) bfr[c] = *(const bf16x8*)&Bs[(wn * 32 + c * 16 + ln) * 32 + qg * 8];
#pragma unroll
        for (int r = 0; r < 4; ++r)
#pragma unroll
            for (int c = 0; c < 2; ++c)
                acc[r][c] = __builtin_amdgcn_mfma_f32_16x16x32_bf16(af[r], bfr[c], acc[r][c], 0, 0, 0);
        __syncthreads();
    }
#pragma unroll
    for (int c = 0; c < 2; ++c) {
        int col = n0 + wn * 32 + c * 16 + ln;
        float bb = bias[col];
#pragma unroll
        for (int r = 0; r < 4; ++r) {
#pragma unroll
            for (int i = 0; i < 4; ++i) {
                int row = m0 + wm * 64 + r * 16 + qg * 4 + i;
                Cf[(size_t)row * E_ + col] = acc[r][c][i] + bb;
            }
        }
    }
}

// ---------------- flash attention: S^T formulation, register-only P, K=32 PV ----------
// S^T = K Q^T (A=K,B=Q) => reg i holds key qg*4+i, col q=ln. P^T packed in-register;
// PV pairs two 16-key groups into one K=32 MFMA (same key<->k mapping in A and B).
__global__ __launch_bounds__(256, 4) void attn_kernel(
    const u16* __restrict__ Q, const u16* __restrict__ K, const u16* __restrict__ Vt,
    const int* __restrict__ seq_len, const float* __restrict__ vmean,
    u16* __restrict__ ctx, u16* __restrict__ Opart, float* __restrict__ Lpart)
{
    __shared__ u16 Ks[2][64][72];   // [buf][key][feat]
    __shared__ u16 Vs[2][64][72];   // [buf][d][key]

    const int tid = threadIdx.x, wave = tid >> 6, lane = tid & 63;
    const int qg = lane >> 4, ln = lane & 15;
    const int bh = blockIdx.x & 31;
    const int code = ATTN_MAP[blockIdx.x >> 5];
    const int qt = code >> 2, ck = code & 3;
    const int b = bh >> 4, h = bh & 15;
    const int q0 = qt * 64;
    const int seq = seq_len[b];
    if (seq <= q0) return;                       // combine writes vmean rows

    const int kend_band = min(q0 + 64, seq);
    const int nch = (kend_band + 511) >> 9;
    if (ck >= nch) return;
    const bool direct = (nch == 1);
    const int kstart = ck << 9;
    const int kend_c = min(kend_band, kstart + 512);
    const int ntiles = (kend_c - kstart + 63) >> 6;
    const int wq0 = q0 + wave * 16;
    const int qr = wq0 + ln;                     // this lane's q-row

    // Q B-fragments
    bf16x8 qa[2];
    {
        const u16* qp = Q + (size_t)(b * L_ + qr) * E_ + h * 64;
        qa[0] = *(const bf16x8*)(qp + qg * 8);
        qa[1] = *(const bf16x8*)(qp + 32 + qg * 8);
    }

    f32x4 ot[4] = {};          // O^T: d = dt*16 + qg*4 + i, q = ln
    float lsum = 0.f;

    const int sr = tid >> 3, ss = (tid & 7) * 8;
    const u16* kbase = K + (size_t)(b * L_) * E_ + h * 64;
    const u16* vbase = Vt + (size_t)bh * 64 * L_;

    uint4 rk0 = *(const uint4*)(kbase + (size_t)(kstart + sr) * E_ + ss);
    uint4 rk1 = *(const uint4*)(kbase + (size_t)(kstart + sr + 32) * E_ + ss);
    uint4 rv0 = *(const uint4*)(vbase + (size_t)sr * L_ + kstart + ss);
    uint4 rv1 = *(const uint4*)(vbase + (size_t)(sr + 32) * L_ + kstart + ss);

    for (int kt = 0; kt < ntiles; ++kt) {
        const int kb0 = kstart + kt * 64;
        const int buf = kt & 1;
        *(uint4*)&Ks[buf][sr][ss]      = rk0;
        *(uint4*)&Ks[buf][sr + 32][ss] = rk1;
        *(uint4*)&Vs[buf][sr][ss]      = rv0;
        *(uint4*)&Vs[buf][sr + 32][ss] = rv1;
        __syncthreads();

        if (kt + 1 < ntiles) {
            const int kn = kb0 + 64;
            rk0 = *(const uint4*)(kbase + (size_t)(kn + sr) * E_ + ss);
            rk1 = *(const uint4*)(kbase + (size_t)(kn + sr + 32) * E_ + ss);
            rv0 = *(const uint4*)(vbase + (size_t)sr * L_ + kn + ss);
            rv1 = *(const uint4*)(vbase + (size_t)(sr + 32) * L_ + kn + ss);
        }

        // S^T = K Q^T: 4 key-tiles of 16 (keys kb0 + c*16 + qg*4 + i per reg)
        f32x4 st[4] = {};
#pragma unroll
        for (int t = 0; t < 2; ++t) {
#pragma unroll
            for (int c = 0; c < 4; ++c) {
                bf16x8 kb = *(const bf16x8*)&Ks[buf][c * 16 + ln][t * 32 + qg * 8];
                st[c] = __builtin_amdgcn_mfma_f32_16x16x32_bf16(kb, qa[t], st[c], 0, 0, 0);
            }
        }

        // softmax numerator in-register; pack P^T per 16-key group
        const bool need_mask = (kb0 + 63) > wq0;
        uint2 pk[4];
#pragma unroll
        for (int c = 0; c < 4; ++c) {
            const int keyb = kb0 + c * 16 + qg * 4;
            float p0 = exp2f(st[c][0]);
            float p1 = exp2f(st[c][1]);
            float p2 = exp2f(st[c][2]);
            float p3 = exp2f(st[c][3]);
            if (need_mask) {
                if (keyb > qr)     p0 = 0.f;
                if (keyb + 1 > qr) p1 = 0.f;
                if (keyb + 2 > qr) p2 = 0.f;
                if (keyb + 3 > qr) p3 = 0.f;
            }
            lsum += (p0 + p1) + (p2 + p3);
            pk[c].x = f2bu(p0) | (f2bu(p1) << 16);
            pk[c].y = f2bu(p2) | (f2bu(p3) << 16);
        }

        // O^T += V * P^T, K=32: pair key-groups (0,1) and (2,3). A slot j=0..3 from
        // group 2cp, j=4..7 from group 2cp+1 — same key<->k map as B (pk concat).
#pragma unroll
        for (int cp = 0; cp < 2; ++cp) {
            union { uint4 u; bf16x8 v; } pbp;
            pbp.u = make_uint4(pk[2 * cp].x, pk[2 * cp].y, pk[2 * cp + 1].x, pk[2 * cp + 1].y);
#pragma unroll
            for (int dt = 0; dt < 4; ++dt) {
                union { struct { s16x4 lo, hi; } h; bf16x8 v; } vf;
                vf.h.lo = *(const s16x4*)&Vs[buf][dt * 16 + ln][(2 * cp) * 16 + qg * 4];
                vf.h.hi = *(const s16x4*)&Vs[buf][dt * 16 + ln][(2 * cp + 1) * 16 + qg * 4];
                ot[dt] = __builtin_amdgcn_mfma_f32_16x16x32_bf16(vf.v, pbp.v, ot[dt], 0, 0, 0);
            }
        }
    }

    // lsum: in-lane keys done; reduce across the 4 quad-groups (same q=ln)
    lsum += __shfl_xor(lsum, 16);
    lsum += __shfl_xor(lsum, 32);

    if (direct) {
        bool valid = qr < seq;
        float inv = valid ? (1.0f / lsum) : 0.f;
        u16* cp = ctx + ((size_t)(b * L_ + qr)) * E_ + h * 64;
#pragma unroll
        for (int dt = 0; dt < 4; ++dt) {
            uint2 w;
            if (valid) {
                w.x = f2bu(ot[dt][0] * inv) | (f2bu(ot[dt][1] * inv) << 16);
                w.y = f2bu(ot[dt][2] * inv) | (f2bu(ot[dt][3] * inv) << 16);
            } else {
                const float* vm = vmean + bh * 64 + dt * 16 + qg * 4;
                w.x = f2bu(vm[0]) | (f2bu(vm[1]) << 16);
                w.y = f2bu(vm[2]) | (f2bu(vm[3]) << 16);
            }
            *(uint2*)(cp + dt * 16 + qg * 4) = w;
        }
    } else {
        const int slot = slot_base(qt) + ck;
        const size_t pbase = ((size_t)bh * 72 + slot) * 64 + wave * 16 + ln;
        u16* op = Opart + pbase * 64;
#pragma unroll
        for (int dt = 0; dt < 4; ++dt) {
            uint2 w;
            w.x = f2bu(ot[dt][0]) | (f2bu(ot[dt][1]) << 16);
            w.y = f2bu(ot[dt][2]) | (f2bu(ot[dt][3]) << 16);
            *(uint2*)(op + dt * 16 + qg * 4) = w;
        }
        if (qg == 0) Lpart[pbase] = lsum;
    }
}

// ---------------- merge chunk partials, normalize, write ctx ----------------
__global__ __launch_bounds__(256) void attn_combine(
    const u16* __restrict__ Opart, const float* __restrict__ Lpart,
    const int* __restrict__ seq_len, const float* __restrict__ vmean,
    u16* __restrict__ ctx)
{
    const int qt = blockIdx.x, h = blockIdx.y, b = blockIdx.z;
    const int seq = seq_len[b];
    const int q0 = qt * 64;
    const int bh = b * H_ + h;
    int nch = 0;
    if (seq > q0) {
        nch = (min(q0 + 64, seq) + 511) >> 9;
        if (nch == 1) return;            // band written directly by attn_kernel
    }
    const int row = threadIdx.x >> 2, quar = threadIdx.x & 3;
    const int qr = q0 + row;
    u16* dst = ctx + ((size_t)(b * L_ + qr)) * E_ + h * 64 + quar * 16;
    if (qr >= seq) {
        u16 t[16];
#pragma unroll
        for (int j = 0; j < 16; ++j) t[j] = f2b(vmean[bh * 64 + quar * 16 + j]);
        *(uint4*)dst = *(uint4*)t;
        *(uint4*)(dst + 8) = *(uint4*)(t + 8);
        return;
    }
    const int sb = slot_base(qt);
    float acc[16] = {};
    float lt = 0.f;
    for (int ck = 0; ck < nch; ++ck) {
        const size_t pb = ((size_t)bh * 72 + sb + ck) * 64 + row;
        lt += Lpart[pb];
        const u16* op = Opart + pb * 64 + quar * 16;
        u16 t[16];
        *(uint4*)t       = *(const uint4*)op;
        *(uint4*)(t + 8) = *(const uint4*)(op + 8);
#pragma unroll
        for (int j = 0; j < 16; ++j) acc[j] += b2f(t[j]);
    }
    const float inv = 1.0f / lt;
    u16 t[16];
#pragma unroll
    for (int j = 0; j < 16; ++j) t[j] = f2b(acc[j] * inv);
    *(uint4*)dst = *(uint4*)t;
    *(uint4*)(dst + 8) = *(uint4*)(t + 8);
}

extern "C" void kernel_launch(void* const* d_in, const int* in_sizes, int n_in,
                              void* d_out, int out_size, void* d_ws, size_t ws_size,
                              hipStream_t stream) {
    const float* hs = (const float*)d_in[0];
    const int*   seq = (const int*)d_in[1];
    const float* Wq = (const float*)d_in[2];
    const float* bq = (const float*)d_in[3];
    const float* Wk = (const float*)d_in[4];
    const float* Wv = (const float*)d_in[5];
    const float* bv = (const float*)d_in[6];
    const float* Wo = (const float*)d_in[7];
    const float* bo = (const float*)d_in[8];
    float* out = (float*)d_out;

    char* ws = (char*)d_ws;
    u16* hs_b  = (u16*)(ws);                          // 8 MB
    u16* wq_b  = (u16*)(ws + ((size_t)8  << 20));
    u16* wk_b  = (u16*)(ws + ((size_t)10 << 20));
    u16* wv_b  = (u16*)(ws + ((size_t)12 << 20));
    u16* wo_b  = (u16*)(ws + ((size_t)14 << 20));
    u16* q_b   = (u16*)(ws + ((size_t)16 << 20));     // 8 MB
    u16* k_b   = (u16*)(ws + ((size_t)24 << 20));     // 8 MB
    u16* vt    = (u16*)(ws + ((size_t)32 << 20));     // 8 MB (transposed V)
    u16* ctx_b = (u16*)(ws + ((size_t)40 << 20));     // 8 MB
    u16* Opart = (u16*)(ws + ((size_t)48 << 20));     // 18.9 MB (72 slots x 32bh x 4096 bf16)
    float* Lpart = (float*)(ws + ((size_t)67 << 20)); // 590 KB
    float* vmean = (float*)(ws + ((size_t)68 << 20)); // 8 KB

    cast_all<<<8193, 256, 0, stream>>>(hs, Wq, Wk, Wv, Wo, hs_b, wq_b, wk_b, wv_b, wo_b, vmean);

    gemm_qkv<<<dim3(M_/128, 3*E_/128), 256, 0, stream>>>(hs_b, wq_b, wk_b, wv_b, bq, bv,
                                                         q_b, k_b, vt, vmean);

    attn_kernel<<<dim3(80 * 32), 256, 0, stream>>>(q_b, k_b, vt, seq, vmean,
                                                   ctx_b, Opart, Lpart);

    attn_combine<<<dim3(32, H_, B_), 256, 0, stream>>>(Opart, Lpart, seq, vmean, ctx_b);

    gemm_out<<<dim3(M_/128, E_/64), 256, 0, stream>>>(ctx_b, wo_b, bo, out);
}